// Round 5
// baseline (478.496 us; speedup 1.0000x reference)
//
#include <hip/hip_runtime.h>
#include <math.h>

#define Bn 4
#define Tn 4096
#define Dn 1024
#define Nn 64
#define Rn 16
#define KCONV 4

#define TT2 32    // t-rows per prep block
#define KCH 32    // K-chunk (one 16x16x32 MFMA K-step)
#define SU 32     // scan chunk (steps per prefetch block)

typedef __attribute__((ext_vector_type(8))) short bf16x8;
typedef __attribute__((ext_vector_type(4))) float f32x4;

__device__ __forceinline__ unsigned short bf16_rne(float f) {
    unsigned int u = __float_as_uint(f);
    unsigned int r = (u + 0x7fffu + ((u >> 16) & 1u)) >> 16;
    return (unsigned short)r;
}

// Layout: intermediates live INSIDE d_out, TRANSPOSED per 64-row tile.
// For tile t0' = t & ~63 (64 consecutive t rows of one batch):
//   element (t, n) of P  -> O[(b*Tn + t0' + n)*Dn +   0 + (t - t0')]
//   element (t, n) of Dl -> O[(b*Tn + t0' + n)*Dn +  64 + (t - t0')]
//   element (t, n) of S  -> O[(b*Tn + t0' + n)*Dn + 128 + (t - t0')]
// Scan lane n's data is contiguous over t within each tile. out_kernel only
// touches its own 64 rows before overwriting them. Race-free, no d_ws usage.

// ---------------------------------------------------------------------------
// Kernel 1 (MFMA bf16x3): fused conv + input proj + delta path. (unchanged)
// ---------------------------------------------------------------------------
__global__ __launch_bounds__(128)
void prep_kernel(const float* __restrict__ x, const float* __restrict__ conv_w,
                 const float* __restrict__ in_w, const float* __restrict__ in_b,
                 const float* __restrict__ dt_w, const float* __restrict__ dt_b,
                 const float* __restrict__ tr_w,
                 float* __restrict__ O)
{
    __shared__ bf16x8 Axc_h[2][64], Axc_l[2][64];
    __shared__ bf16x8 Axr_h[2][64], Axr_l[2][64];
    __shared__ bf16x8 Bw_h[4][64],  Bw_l[4][64];
    __shared__ bf16x8 Bd_h[64],     Bd_l[64];
    __shared__ float  AsS[TT2][17];
    __shared__ float  trS[Nn][17];

    const int tid = threadIdx.x;
    const int b   = blockIdx.y;
    const int t0  = blockIdx.x * TT2;
    const int l   = tid & 63;
    const int w   = tid >> 6;

    const float* xb = x + (size_t)b * Tn * Dn;

    for (int idx = tid; idx < Nn * Rn; idx += 128)
        trS[idx >> 4][idx & 15] = tr_w[idx];

    const f32x4 z4 = {0.f, 0.f, 0.f, 0.f};
    f32x4 accP[4] = {z4, z4, z4, z4};
    f32x4 accG = z4;

    for (int kc = 0; kc < Dn / KCH; ++kc) {
        const int k0 = kc * KCH;
        __syncthreads();

        {
            const int m  = tid & 31;
            const int s  = tid >> 5;
            const int t  = t0 + m;
            const int gk = k0 + 8 * s;
            float v[4][8];
            #pragma unroll
            for (int dr = 0; dr < 4; ++dr) {
                int tp = t - 3 + dr;
                if (tp >= 0) {
                    float4 a  = *(const float4*)&xb[(size_t)tp * Dn + gk];
                    float4 bq = *(const float4*)&xb[(size_t)tp * Dn + gk + 4];
                    v[dr][0]=a.x;  v[dr][1]=a.y;  v[dr][2]=a.z;  v[dr][3]=a.w;
                    v[dr][4]=bq.x; v[dr][5]=bq.y; v[dr][6]=bq.z; v[dr][7]=bq.w;
                } else {
                    #pragma unroll
                    for (int k = 0; k < 8; ++k) v[dr][k] = 0.f;
                }
            }
            bf16x8 fch, fcl, frh, frl;
            #pragma unroll
            for (int k = 0; k < 8; ++k) {
                float4 cw = *(const float4*)&conv_w[(size_t)(gk + k) * 4];
                float xr = v[3][k];
                float xc = xr;
                xc = fmaf(v[0][k], cw.x, xc);
                xc = fmaf(v[1][k], cw.y, xc);
                xc = fmaf(v[2][k], cw.z, xc);
                xc = fmaf(v[3][k], cw.w, xc);
                unsigned short h; float hf;
                h = bf16_rne(xc); hf = __uint_as_float((unsigned)h << 16);
                fch[k] = (short)h; fcl[k] = (short)bf16_rne(xc - hf);
                h = bf16_rne(xr); hf = __uint_as_float((unsigned)h << 16);
                frh[k] = (short)h; frl[k] = (short)bf16_rne(xr - hf);
            }
            const int lane = (m & 15) | (s << 4), mt = m >> 4;
            Axc_h[mt][lane] = fch; Axc_l[mt][lane] = fcl;
            Axr_h[mt][lane] = frh; Axr_l[mt][lane] = frl;
        }
        #pragma unroll
        for (int rep = 0; rep < 2; ++rep) {
            int slot = tid + rep * 128;
            int n = slot & 63, s = slot >> 6;
            const float* wp = &in_w[(size_t)n * Dn + k0 + 8 * s];
            float4 a  = *(const float4*)wp;
            float4 bq = *(const float4*)(wp + 4);
            float wv[8] = {a.x, a.y, a.z, a.w, bq.x, bq.y, bq.z, bq.w};
            bf16x8 fh, fl;
            #pragma unroll
            for (int k = 0; k < 8; ++k) {
                unsigned short h = bf16_rne(wv[k]);
                float hf = __uint_as_float((unsigned)h << 16);
                fh[k] = (short)h; fl[k] = (short)bf16_rne(wv[k] - hf);
            }
            Bw_h[n >> 4][(n & 15) | (s << 4)] = fh;
            Bw_l[n >> 4][(n & 15) | (s << 4)] = fl;
        }
        if (tid < 64) {
            int r = tid & 15, s = tid >> 4;
            const float* wp = &dt_w[(size_t)r * Dn + k0 + 8 * s];
            float4 a  = *(const float4*)wp;
            float4 bq = *(const float4*)(wp + 4);
            float wv[8] = {a.x, a.y, a.z, a.w, bq.x, bq.y, bq.z, bq.w};
            bf16x8 fh, fl;
            #pragma unroll
            for (int k = 0; k < 8; ++k) {
                unsigned short h = bf16_rne(wv[k]);
                float hf = __uint_as_float((unsigned)h << 16);
                fh[k] = (short)h; fl[k] = (short)bf16_rne(wv[k] - hf);
            }
            Bd_h[tid] = fh; Bd_l[tid] = fl;
        }
        __syncthreads();

        bf16x8 axh = Axc_h[w][l], axl = Axc_l[w][l];
        bf16x8 arh = Axr_h[w][l], arl = Axr_l[w][l];
        #pragma unroll
        for (int nt = 0; nt < 4; ++nt) {
            bf16x8 bh = Bw_h[nt][l], bl = Bw_l[nt][l];
            accP[nt] = __builtin_amdgcn_mfma_f32_16x16x32_bf16(axh, bh, accP[nt], 0, 0, 0);
            accP[nt] = __builtin_amdgcn_mfma_f32_16x16x32_bf16(axl, bh, accP[nt], 0, 0, 0);
            accP[nt] = __builtin_amdgcn_mfma_f32_16x16x32_bf16(axh, bl, accP[nt], 0, 0, 0);
        }
        {
            bf16x8 bh = Bd_h[l], bl = Bd_l[l];
            accG = __builtin_amdgcn_mfma_f32_16x16x32_bf16(arh, bh, accG, 0, 0, 0);
            accG = __builtin_amdgcn_mfma_f32_16x16x32_bf16(arl, bh, accG, 0, 0, 0);
            accG = __builtin_amdgcn_mfma_f32_16x16x32_bf16(arh, bl, accG, 0, 0, 0);
        }
    }

    __syncthreads();
    #pragma unroll
    for (int i = 0; i < 4; ++i)
        AsS[16 * w + 4 * (l >> 4) + i][l & 15] = tanhf(accG[i] + dt_b[l & 15]);
    __syncthreads();

    float as_[4][16];
    #pragma unroll
    for (int i = 0; i < 4; ++i) {
        int mrow = 16 * w + 4 * (l >> 4) + i;
        #pragma unroll
        for (int j = 0; j < 4; ++j) {
            float4 q = *(const float4*)&AsS[mrow][4 * j];
            as_[i][4*j] = q.x; as_[i][4*j+1] = q.y;
            as_[i][4*j+2] = q.z; as_[i][4*j+3] = q.w;
        }
    }
    const int tile0 = t0 & ~63;
    const int coff  = t0 & 63;
    #pragma unroll
    for (int nt = 0; nt < 4; ++nt) {
        int n = 16 * nt + (l & 15);
        float tw[16];
        #pragma unroll
        for (int j = 0; j < 4; ++j) {
            float4 q = *(const float4*)&trS[n][4 * j];
            tw[4*j] = q.x; tw[4*j+1] = q.y; tw[4*j+2] = q.z; tw[4*j+3] = q.w;
        }
        float ib = in_b[n];
        #pragma unroll
        for (int i = 0; i < 4; ++i) {
            int mrow = 16 * w + 4 * (l >> 4) + i;
            float dlv = 0.f;
            #pragma unroll
            for (int r = 0; r < 16; ++r) dlv = fmaf(as_[i][r], tw[r], dlv);
            size_t a = ((size_t)(b * Tn + tile0 + n)) * Dn + coff + mrow;
            O[a]      = accP[nt][i] + ib;
            O[a + 64] = dlv;
        }
    }
}

// ---------------------------------------------------------------------------
// Kernel 2: sequential scan, DMA double-buffered through LDS.
// grid (B), block 64 (1 wave). global_load_lds prefetches chunk c+1 while
// the serial silu chain chews chunk c from LDS. Regalloc can't touch DMA.
// ---------------------------------------------------------------------------
__global__ __launch_bounds__(64, 1)
void scan_kernel(float* __restrict__ O)
{
    __shared__ f32x4 LP[2][8][64];   // [buf][col-group][lane]
    __shared__ f32x4 LD[2][8][64];

    const int b = blockIdx.x;
    const int n = threadIdx.x;
    float* obase = O + (size_t)b * Tn * Dn;
    const float L2E = 1.44269504088896340736f;

    // issue 16 DMA loads (P and Dl col-groups) for chunk at t0 into buffer bf
    #define ISSUE_CHUNK(t0_, bf_)                                                 \
        do {                                                                      \
            const int _tile = (t0_) & ~63, _coff = (t0_) & 63;                    \
            const float* _gp = obase + (size_t)(_tile + n) * Dn + _coff;          \
            _Pragma("unroll")                                                     \
            for (int g = 0; g < 8; ++g)                                           \
                __builtin_amdgcn_global_load_lds(                                 \
                    (const __attribute__((address_space(1))) void*)(_gp + 4 * g), \
                    (__attribute__((address_space(3))) void*)&LP[bf_][g][0],      \
                    16, 0, 0);                                                    \
            _Pragma("unroll")                                                     \
            for (int g = 0; g < 8; ++g)                                           \
                __builtin_amdgcn_global_load_lds(                                 \
                    (const __attribute__((address_space(1))) void*)(_gp + 64 + 4 * g), \
                    (__attribute__((address_space(3))) void*)&LD[bf_][g][0],      \
                    16, 0, 0);                                                    \
        } while (0)

    ISSUE_CHUNK(0, 0);

    float st = 0.f;
    const int NC = Tn / SU;
    for (int c = 0; c < NC; ++c) {
        const int t0 = c * SU;
        // prefetch next chunk (last iter: dummy re-fetch of chunk 0 into the
        // dead buffer, keeping the vmcnt invariant unconditional)
        const int tnext = (c + 1 < NC) ? (t0 + SU) : 0;
        ISSUE_CHUNK(tnext, (c + 1) & 1);

        // 16 newest outstanding VM ops = the DMAs just issued; waiting down to
        // 16 drains current chunk's DMAs (and all older stores).
        asm volatile("s_waitcnt vmcnt(16)" ::: "memory");

        const int bf = c & 1;
        f32x4 pc[8], dc[8];
        #pragma unroll
        for (int g = 0; g < 8; ++g) { pc[g] = LP[bf][g][n]; dc[g] = LD[bf][g][n]; }

        float* sp = obase + (size_t)((t0 & ~63) + n) * Dn + 128 + (t0 & 63);
        #pragma unroll
        for (int j = 0; j < 8; ++j) {
            #pragma unroll
            for (int i = 0; i < 4; ++i) {
                float d  = dc[j][i];
                float dL = d * L2E;                     // off critical chain
                float u  = st + d;                      // off critical chain
                float e  = __builtin_amdgcn_exp2f(fmaf(st, -L2E, -dL));
                float r  = __builtin_amdgcn_rcpf(1.f + e);
                st = fmaf(u, r, pc[j][i]);
                pc[j][i] = st;
            }
            *(f32x4*)(sp + 4 * j) = pc[j];
        }
    }
    #undef ISSUE_CHUNK
}

// ---------------------------------------------------------------------------
// Kernel 3: output projection, in-place. (unchanged from R4)
// ---------------------------------------------------------------------------
__global__ __launch_bounds__(256)
void out_kernel(const float* __restrict__ out_w, const float* __restrict__ out_b,
                float* __restrict__ O)
{
    __shared__ float Ss[64][Nn + 4];
    __shared__ float wT[Nn][64 + 4];

    const int tid = threadIdx.x;
    const int r0  = blockIdx.x * 64;
    const int c   = tid & 15;
    const int g   = tid >> 4;

    for (int idx = tid; idx < 64 * 16; idx += 256) {
        int nn = idx >> 4, tg = idx & 15;
        float4 v = *(const float4*)&O[(size_t)(r0 + nn) * Dn + 128 + 4 * tg];
        Ss[4 * tg + 0][nn] = v.x;
        Ss[4 * tg + 1][nn] = v.y;
        Ss[4 * tg + 2][nn] = v.z;
        Ss[4 * tg + 3][nn] = v.w;
    }
    __syncthreads();

    for (int cb = 0; cb < Dn / 64; ++cb) {
        const int d0 = cb * 64;
        for (int idx = tid; idx < Nn * 64 / 4; idx += 256) {
            int dl = idx >> 4, n4 = (idx & 15) * 4;
            float4 wv = *(const float4*)&out_w[(size_t)(d0 + dl) * Nn + n4];
            wT[n4 + 0][dl] = wv.x;
            wT[n4 + 1][dl] = wv.y;
            wT[n4 + 2][dl] = wv.z;
            wT[n4 + 3][dl] = wv.w;
        }
        __syncthreads();

        float acc[4][4] = {};
        #pragma unroll
        for (int kq = 0; kq < Nn; kq += 4) {
            float4 wv0 = *(const float4*)&wT[kq + 0][4 * c];
            float4 wv1 = *(const float4*)&wT[kq + 1][4 * c];
            float4 wv2 = *(const float4*)&wT[kq + 2][4 * c];
            float4 wv3 = *(const float4*)&wT[kq + 3][4 * c];
            #pragma unroll
            for (int i = 0; i < 4; ++i) {
                int row = g + 16 * i;
                float4 xv = *(const float4*)&Ss[row][kq];
                acc[i][0] = fmaf(xv.x, wv0.x, fmaf(xv.y, wv1.x, fmaf(xv.z, wv2.x, fmaf(xv.w, wv3.x, acc[i][0]))));
                acc[i][1] = fmaf(xv.x, wv0.y, fmaf(xv.y, wv1.y, fmaf(xv.z, wv2.y, fmaf(xv.w, wv3.y, acc[i][1]))));
                acc[i][2] = fmaf(xv.x, wv0.z, fmaf(xv.y, wv1.z, fmaf(xv.z, wv2.z, fmaf(xv.w, wv3.z, acc[i][2]))));
                acc[i][3] = fmaf(xv.x, wv0.w, fmaf(xv.y, wv1.w, fmaf(xv.z, wv2.w, fmaf(xv.w, wv3.w, acc[i][3]))));
            }
        }

        float4 bb = *(const float4*)&out_b[d0 + 4 * c];
        #pragma unroll
        for (int i = 0; i < 4; ++i) {
            int row = g + 16 * i;
            float4 o = make_float4(acc[i][0] + bb.x, acc[i][1] + bb.y,
                                   acc[i][2] + bb.z, acc[i][3] + bb.w);
            *(float4*)&O[(size_t)(r0 + row) * Dn + d0 + 4 * c] = o;
        }
        __syncthreads();
    }
}

extern "C" void kernel_launch(void* const* d_in, const int* in_sizes, int n_in,
                              void* d_out, int out_size, void* d_ws, size_t ws_size,
                              hipStream_t stream)
{
    const float* x      = (const float*)d_in[0];
    const float* conv_w = (const float*)d_in[1];
    const float* in_w   = (const float*)d_in[2];
    const float* in_b   = (const float*)d_in[3];
    const float* dt_w   = (const float*)d_in[4];
    const float* dt_b   = (const float*)d_in[5];
    const float* tr_w   = (const float*)d_in[6];
    const float* out_w  = (const float*)d_in[7];
    const float* out_b  = (const float*)d_in[8];
    float* O = (float*)d_out;
    (void)d_ws; (void)ws_size;

    dim3 g1(Tn / TT2, Bn);
    prep_kernel<<<g1, 128, 0, stream>>>(x, conv_w, in_w, in_b, dt_w, dt_b, tr_w, O);

    scan_kernel<<<dim3(Bn), 64, 0, stream>>>(O);

    out_kernel<<<dim3((Bn * Tn) / 64), 256, 0, stream>>>(out_w, out_b, O);
}